// Round 7
// baseline (441.795 us; speedup 1.0000x reference)
//
#include <hip/hip_runtime.h>
#include <hip/hip_bf16.h>

#define N 8192
#define HID 64
#define JC 8    // J-chunks per I-tile: grid = 128*JC = 1024 blocks, 4/CU resident

typedef __attribute__((ext_vector_type(4))) float f32x4;
typedef __attribute__((ext_vector_type(8))) __bf16 bf16x8;

// async global->LDS, 16B per lane, dest = wave-uniform base + lane*16
__device__ __forceinline__ void gload_lds16(const float* g, float* l) {
  __builtin_amdgcn_global_load_lds(
      (const __attribute__((address_space(1))) void*)g,
      (__attribute__((address_space(3))) void*)l, 16, 0, 0);
}

#define FENCE asm volatile("" ::: "memory")

// ---------------- Kernel A: projection + L2 normalize -> bf16 ----------------
// h = elu(x @ W1^T + b1); z = h @ W2^T + b2; zhat = z / max(||z||, 1e-12)
// One wave per row-iteration; lane j = output feature j. W1/W2 in LDS with
// stride-68 padding. Also zero-inits the 4*N stat array (replaces memset).
__global__ __launch_bounds__(256) void proj_kernel(
    const float* __restrict__ x1, const float* __restrict__ x2,
    const float* __restrict__ W1, const float* __restrict__ b1,
    const float* __restrict__ W2, const float* __restrict__ b2,
    __bf16* __restrict__ Z1h, __bf16* __restrict__ Z2h,
    float* __restrict__ stats)
{
  __shared__ __align__(16) float w1s[64*68];
  __shared__ __align__(16) float w2s[64*68];
  __shared__ __align__(16) float xs[4][64];
  __shared__ __align__(16) float hs[4][64];

  const int tid  = threadIdx.x;
  const int lane = tid & 63;
  const int w    = tid >> 6;

  int gtid = blockIdx.x * 256 + tid;
  if (gtid < 4*N) stats[gtid] = 0.f;

  for (int idx = tid; idx < 64*64; idx += 256) {
    int j = idx >> 6, k = idx & 63;
    w1s[j*68+k] = W1[idx];
    w2s[j*68+k] = W2[idx];
  }
  __syncthreads();

  const float bias1 = b1[lane];
  const float bias2 = b2[lane];

  const int wave_global = blockIdx.x * 4 + w;   // 0..4095 with grid=1024
  #pragma unroll 1
  for (int it = 0; it < 4; ++it) {
    int R = wave_global * 4 + it;               // 0..16383
    const float* src; __bf16* dst;
    if (R < N) { src = x1 + (size_t)R*HID;      dst = Z1h + (size_t)R*HID; }
    else       { src = x2 + (size_t)(R-N)*HID;  dst = Z2h + (size_t)(R-N)*HID; }

    float xv = src[lane];
    xs[w][lane] = xv;
    float acc = bias1;
    #pragma unroll
    for (int qq = 0; qq < 16; ++qq) {
      f32x4 xq = *(const f32x4*)&xs[w][qq*4];
      f32x4 wq = *(const f32x4*)&w1s[lane*68 + qq*4];
      acc += xq.x*wq.x + xq.y*wq.y + xq.z*wq.z + xq.w*wq.w;
    }
    float h = acc > 0.f ? acc : expm1f(acc);             // ELU (alpha=1)
    hs[w][lane] = h;
    float acc2 = bias2;
    #pragma unroll
    for (int qq = 0; qq < 16; ++qq) {
      f32x4 hq = *(const f32x4*)&hs[w][qq*4];
      f32x4 wq = *(const f32x4*)&w2s[lane*68 + qq*4];
      acc2 += hq.x*wq.x + hq.y*wq.y + hq.z*wq.z + hq.w*wq.w;
    }
    float z = acc2;
    float ss = z*z;
    #pragma unroll
    for (int m = 1; m < 64; m <<= 1) ss += __shfl_xor(ss, m);
    float inv = 1.0f / fmaxf(sqrtf(ss), 1e-12f);
    dst[lane] = (__bf16)(z * inv);
  }
}

// ---------------- Kernel B: exp-sim, fully pipelined pos(LDS) + Z(regs) -----
// pos: async global_load_lds double-buffer, wave-private (no __syncthreads),
//   staged one 64-col super-step ahead. Source-swizzled slot^(row&7) so the
//   linear LDS dest yields conflict-free swizzled reads (verified absmax 0, R6).
// Z:  j-fragments prefetched into named A/B register banks one 32-col
//   half-step ahead (8 dwordx4 per bank), issued BEFORE the pos wait.
// Ledger discipline: VMEM issue order is pinned with empty memory-clobber asm;
//   every vmcnt(12) leaves exactly the 12 just-issued loads (8 Z + 4 pos) in
//   flight and waits only for loads issued >= one half-step earlier. No wait
//   in the main loop ever drains a just-issued load.
// Swapped-operand MFMA (verified): lane (q,r16), reg r = element
//   (i = i0+r16, j = j0+c*16+q*4+r) -> pos quad = one f32x4 from LDS.
__global__ __launch_bounds__(256) void sim_kernel(
    const __bf16* __restrict__ Z1h, const __bf16* __restrict__ Z2h,
    const float* __restrict__ pos,
    float* __restrict__ rowsum1, float* __restrict__ num1,
    float* __restrict__ rowsum2, float* __restrict__ num2)
{
  __shared__ __align__(16) float pbuf[2][64][64];   // 32 KB double buffer

  const int tid  = threadIdx.x;
  const int lane = tid & 63;
  const int w    = tid >> 6;
  const int r16  = lane & 15;
  const int q    = lane >> 4;

  const int bi  = blockIdx.x / JC;    // 0..127 I-tile
  const int jc  = blockIdx.x % JC;
  const int i0b = bi*64;
  const int i0  = i0b + w*16;

  // i-side fragments: row i0+r16, k = q*8 (lo) / +32 (hi)
  const __bf16* z1r = Z1h + (size_t)(i0 + r16)*HID + q*8;
  const __bf16* z2r = Z2h + (size_t)(i0 + r16)*HID + q*8;
  const bf16x8 a1lo = *(const bf16x8*)(z1r);
  const bf16x8 a1hi = *(const bf16x8*)(z1r + 32);
  const bf16x8 a2lo = *(const bf16x8*)(z2r);
  const bf16x8 a2hi = *(const bf16x8*)(z2r + 32);

  float s1 = 0.f, n1 = 0.f, s2 = 0.f, n2 = 0.f;

  const int jbeg = jc * (N/JC);               // 1024-col chunk, 16 x 64-col steps
  const float Cexp = 1.8033688011112042f;     // 1/(TAU*ln2), TAU=0.8

  // Z register banks: 8 fragments each (one 32-col half-step)
  bf16x8 Ab2l0, Ab2h0, Ab1l0, Ab1h0, Ab2l1, Ab2h1, Ab1l1, Ab1h1;
  bf16x8 Bb2l0, Bb2h0, Bb1l0, Bb1h0, Bb2l1, Bb2h1, Bb1l1, Bb1h1;

  // stage one 64-col pos tile for this wave's 16 rows: 4 x global_load_lds
  // lane l -> LDS row (w*16+rr*4+(l>>4)), 16B slot (l&15); global source
  // col-slot = slot ^ (row&7)  (inverse of the read-side swizzle)
#define STAGE(BUF, JJ) { \
    _Pragma("unroll") \
    for (int rr = 0; rr < 4; ++rr) { \
      int row_t = w*16 + rr*4 + (lane >> 4); \
      int slot  = lane & 15; \
      const float* gsrc = pos + (size_t)(i0b + row_t)*N + (JJ) + (((slot ^ (row_t & 7))) << 2); \
      gload_lds16(gsrc, &pbuf[BUF][w*16 + rr*4][0]); \
    } }

  // load one half-step (32 cols) of Z j-fragments into bank P (8 dwordx4)
#define LOADZ(P, J0) { \
    const __bf16* zj2a = Z2h + (size_t)((J0) + r16)*HID + q*8; \
    const __bf16* zj1a = Z1h + (size_t)((J0) + r16)*HID + q*8; \
    const __bf16* zj2b = Z2h + (size_t)((J0) + 16 + r16)*HID + q*8; \
    const __bf16* zj1b = Z1h + (size_t)((J0) + 16 + r16)*HID + q*8; \
    P##b2l0 = *(const bf16x8*)(zj2a); P##b2h0 = *(const bf16x8*)(zj2a + 32); \
    P##b1l0 = *(const bf16x8*)(zj1a); P##b1h0 = *(const bf16x8*)(zj1a + 32); \
    P##b2l1 = *(const bf16x8*)(zj2b); P##b2h1 = *(const bf16x8*)(zj2b + 32); \
    P##b1l1 = *(const bf16x8*)(zj1b); P##b1h1 = *(const bf16x8*)(zj1b + 32); \
  }

  // one 16x16 j-subtile: MFMA pair + exp + accumulate (C = 0 or 1 literal)
#define COMPC(P, C, CC) { \
    int g = ((CC) >> 2) + (C)*4 + q; \
    int s = g ^ (r16 & 7); \
    f32x4 pv = *(const f32x4*)&pbuf[buf][w*16 + r16][s*4]; \
    f32x4 zero4 = {0.f,0.f,0.f,0.f}; \
    f32x4 d1 = __builtin_amdgcn_mfma_f32_16x16x32_bf16(P##b2l##C, a1lo, zero4, 0,0,0); \
    d1       = __builtin_amdgcn_mfma_f32_16x16x32_bf16(P##b2h##C, a1hi, d1,    0,0,0); \
    f32x4 d2 = __builtin_amdgcn_mfma_f32_16x16x32_bf16(P##b1l##C, a2lo, zero4, 0,0,0); \
    d2       = __builtin_amdgcn_mfma_f32_16x16x32_bf16(P##b1h##C, a2hi, d2,    0,0,0); \
    _Pragma("unroll") \
    for (int r = 0; r < 4; ++r) { \
      float e1 = exp2f(d1[r] * Cexp); \
      float e2 = exp2f(d2[r] * Cexp); \
      s1 += e1; n1 += e1 * pv[r]; \
      s2 += e2; n2 += e2 * pv[r]; \
    } }

#define COMPUTE(P, CC) { COMPC(P, 0, CC) COMPC(P, 1, CC) }

  int buf = 0;
  // prologue: pos(0) and Z(0,h0) in flight
  STAGE(0, jbeg)
  FENCE;
  LOADZ(A, jbeg)
  FENCE;

  #pragma unroll 1
  for (int t = 0; t < 15; ++t) {
    const int jj = jbeg + t*64;
    LOADZ(B, jj + 32)                                   // Z(t,h1)
    FENCE;
    STAGE(buf ^ 1, jj + 64)                             // pos(t+1)
    FENCE;
    asm volatile("s_waitcnt vmcnt(12)" ::: "memory");   // Z(t,h0)+pos(t) landed
    COMPUTE(A, 0)                                       // h0
    FENCE;
    LOADZ(A, jj + 64)                                   // Z(t+1,h0)
    FENCE;
    asm volatile("s_waitcnt vmcnt(12)" ::: "memory");   // Z(t,h1) landed
    COMPUTE(B, 32)                                      // h1
    buf ^= 1;
  }
  // epilogue: t = 15
  {
    const int jj = jbeg + 15*64;
    LOADZ(B, jj + 32)                                   // Z(15,h1)
    FENCE;
    asm volatile("s_waitcnt vmcnt(8)" ::: "memory");    // Z(15,h0)+pos(15) landed
    COMPUTE(A, 0)
    asm volatile("s_waitcnt vmcnt(0)" ::: "memory");
    COMPUTE(B, 32)
  }
#undef STAGE
#undef LOADZ
#undef COMPC
#undef COMPUTE

  // reduce j-partials across the 4 quads -> full sums per row i0+r16
  s1 += __shfl_xor(s1, 16); s1 += __shfl_xor(s1, 32);
  n1 += __shfl_xor(n1, 16); n1 += __shfl_xor(n1, 32);
  s2 += __shfl_xor(s2, 16); s2 += __shfl_xor(s2, 32);
  n2 += __shfl_xor(n2, 16); n2 += __shfl_xor(n2, 32);

  if (lane < 16) {
    int row = i0 + r16;
    atomicAdd(&rowsum1[row], s1);
    atomicAdd(&num1[row],    n1);
    atomicAdd(&rowsum2[row], s2);
    atomicAdd(&num2[row],    n2);
  }
}

// ---------------- Kernel C: final loss reduction ----------------
__global__ __launch_bounds__(1024) void loss_kernel(
    const float* __restrict__ rowsum1, const float* __restrict__ num1,
    const float* __restrict__ rowsum2, const float* __restrict__ num2,
    float* __restrict__ out)
{
  __shared__ float part[16];
  const int tid = threadIdx.x, lane = tid & 63, w = tid >> 6;
  float acc = 0.f;
  for (int i = tid; i < N; i += 1024) {
    float sc = -logf(num1[i]/(rowsum1[i]+1e-8f) + 1e-8f);
    float mp = -logf(num2[i]/(rowsum2[i]+1e-8f) + 1e-8f);
    acc += 0.5f*sc + 0.5f*mp;   // LAMBDA = 0.5
  }
  #pragma unroll
  for (int m = 1; m < 64; m <<= 1) acc += __shfl_xor(acc, m);
  if (lane == 0) part[w] = acc;
  __syncthreads();
  if (tid == 0) {
    float t = 0.f;
    #pragma unroll
    for (int k = 0; k < 16; ++k) t += part[k];
    out[0] = t * (1.0f/N);
  }
}

extern "C" void kernel_launch(void* const* d_in, const int* in_sizes, int n_in,
                              void* d_out, int out_size, void* d_ws, size_t ws_size,
                              hipStream_t stream) {
  const float* x1  = (const float*)d_in[0];
  const float* x2  = (const float*)d_in[1];
  const float* W1  = (const float*)d_in[2];
  const float* b1  = (const float*)d_in[3];
  const float* W2  = (const float*)d_in[4];
  const float* b2  = (const float*)d_in[5];
  const float* pos = (const float*)d_in[6];

  char* ws = (char*)d_ws;
  __bf16* Z1h = (__bf16*)ws;
  __bf16* Z2h = (__bf16*)(ws + (size_t)N*HID*sizeof(__bf16));
  size_t zbytes = (size_t)2*N*HID*sizeof(__bf16);   // 2 MB
  float* rowsum1 = (float*)(ws + zbytes);
  float* num1    = rowsum1 + N;
  float* rowsum2 = num1 + N;
  float* num2    = rowsum2 + N;

  proj_kernel<<<1024, 256, 0, stream>>>(x1, x2, W1, b1, W2, b2, Z1h, Z2h, rowsum1);
  sim_kernel<<<128*JC, 256, 0, stream>>>(Z1h, Z2h, pos, rowsum1, num1, rowsum2, num2);
  loss_kernel<<<1, 1024, 0, stream>>>(rowsum1, num1, rowsum2, num2, (float*)d_out);
}

// Round 8
// 418.968 us; speedup vs baseline: 1.0545x; 1.0545x over previous
//
#include <hip/hip_runtime.h>
#include <hip/hip_bf16.h>

#define N 8192
#define HID 64
#define JC 8    // J-chunks per I-tile: grid = 128*JC = 1024 blocks, 4/CU resident

typedef __attribute__((ext_vector_type(4))) float f32x4;
typedef __attribute__((ext_vector_type(8))) __bf16 bf16x8;

// async global->LDS, 16B per lane, dest = wave-uniform base + lane*16
__device__ __forceinline__ void gload_lds16(const void* g, float* l) {
  __builtin_amdgcn_global_load_lds(
      (const __attribute__((address_space(1))) void*)g,
      (__attribute__((address_space(3))) void*)l, 16, 0, 0);
}

// ---------------- Kernel A: projection + L2 normalize -> bf16 ----------------
// h = elu(x @ W1^T + b1); z = h @ W2^T + b2; zhat = z / max(||z||, 1e-12)
// One wave per row-iteration; lane j = output feature j. W1/W2 in LDS with
// stride-68 padding. Also zero-inits the 4*N stat array (replaces memset).
__global__ __launch_bounds__(256) void proj_kernel(
    const float* __restrict__ x1, const float* __restrict__ x2,
    const float* __restrict__ W1, const float* __restrict__ b1,
    const float* __restrict__ W2, const float* __restrict__ b2,
    __bf16* __restrict__ Z1h, __bf16* __restrict__ Z2h,
    float* __restrict__ stats)
{
  __shared__ __align__(16) float w1s[64*68];
  __shared__ __align__(16) float w2s[64*68];
  __shared__ __align__(16) float xs[4][64];
  __shared__ __align__(16) float hs[4][64];

  const int tid  = threadIdx.x;
  const int lane = tid & 63;
  const int w    = tid >> 6;

  int gtid = blockIdx.x * 256 + tid;
  if (gtid < 4*N) stats[gtid] = 0.f;

  for (int idx = tid; idx < 64*64; idx += 256) {
    int j = idx >> 6, k = idx & 63;
    w1s[j*68+k] = W1[idx];
    w2s[j*68+k] = W2[idx];
  }
  __syncthreads();

  const float bias1 = b1[lane];
  const float bias2 = b2[lane];

  const int wave_global = blockIdx.x * 4 + w;   // 0..4095 with grid=1024
  #pragma unroll 1
  for (int it = 0; it < 4; ++it) {
    int R = wave_global * 4 + it;               // 0..16383
    const float* src; __bf16* dst;
    if (R < N) { src = x1 + (size_t)R*HID;      dst = Z1h + (size_t)R*HID; }
    else       { src = x2 + (size_t)(R-N)*HID;  dst = Z2h + (size_t)(R-N)*HID; }

    float xv = src[lane];
    xs[w][lane] = xv;
    float acc = bias1;
    #pragma unroll
    for (int qq = 0; qq < 16; ++qq) {
      f32x4 xq = *(const f32x4*)&xs[w][qq*4];
      f32x4 wq = *(const f32x4*)&w1s[lane*68 + qq*4];
      acc += xq.x*wq.x + xq.y*wq.y + xq.z*wq.z + xq.w*wq.w;
    }
    float h = acc > 0.f ? acc : expm1f(acc);             // ELU (alpha=1)
    hs[w][lane] = h;
    float acc2 = bias2;
    #pragma unroll
    for (int qq = 0; qq < 16; ++qq) {
      f32x4 hq = *(const f32x4*)&hs[w][qq*4];
      f32x4 wq = *(const f32x4*)&w2s[lane*68 + qq*4];
      acc2 += hq.x*wq.x + hq.y*wq.y + hq.z*wq.z + hq.w*wq.w;
    }
    float z = acc2;
    float ss = z*z;
    #pragma unroll
    for (int m = 1; m < 64; m <<= 1) ss += __shfl_xor(ss, m);
    float inv = 1.0f / fmaxf(sqrtf(ss), 1e-12f);
    dst[lane] = (__bf16)(z * inv);
  }
}

// ---------------- Kernel B: exp-sim, block-cooperative Z-in-LDS ------------
// 2-phase (T3-minimum) schedule, no inline asm:
//   barrier -> STAGE Z(t+1) via global_load_lds (no dest reg => compiler has
//   nothing to conservatively wait on) + issue pos(t+1) reg loads -> COMPUTE(t)
//   from LDS + pos regs -> barrier (its vmcnt(0) drains loads issued a full
//   compute phase earlier => no stall).
// Z j-tiles staged ONCE per block (kills the 4x per-wave redundancy of
// R5-R7). LDS reads XOR-swizzled: content slot s of row R stored at slot
// s^(R&7) (involution; applied on the GLOBAL source at stage time, linear LDS
// dest — same verified idiom as R6's pos staging). Row-major 128B rows would
// otherwise be a 16-way bank conflict (G4).
// pos: per-lane f32x4 loads, double-banked with static names (rule 20).
// Swapped-operand MFMA (verified absmax 0): lane (q,r16), reg r = element
//   (i = i0+r16, j = jj + cc + c*16 + q*4 + r) -> pos quad = one f32x4.
__global__ __launch_bounds__(256, 4) void sim_kernel(
    const __bf16* __restrict__ Z1h, const __bf16* __restrict__ Z2h,
    const float* __restrict__ pos,
    float* __restrict__ rowsum1, float* __restrict__ num1,
    float* __restrict__ rowsum2, float* __restrict__ num2)
{
  __shared__ __align__(16) float zs1[2][2048];   // 64 rows x 128B, double buf
  __shared__ __align__(16) float zs2[2][2048];   // 32 KB total

  const int tid  = threadIdx.x;
  const int lane = tid & 63;
  const int w    = tid >> 6;
  const int r16  = lane & 15;
  const int q    = lane >> 4;

  const int bi  = blockIdx.x / JC;    // 0..127 I-tile
  const int jc  = blockIdx.x % JC;
  const int i0  = bi*64 + w*16;

  // i-side fragments: row i0+r16, k = q*8 (lo) / +32 (hi)
  const __bf16* z1r = Z1h + (size_t)(i0 + r16)*HID + q*8;
  const __bf16* z2r = Z2h + (size_t)(i0 + r16)*HID + q*8;
  const bf16x8 a1lo = *(const bf16x8*)(z1r);
  const bf16x8 a1hi = *(const bf16x8*)(z1r + 32);
  const bf16x8 a2lo = *(const bf16x8*)(z2r);
  const bf16x8 a2hi = *(const bf16x8*)(z2r + 32);

  float s1 = 0.f, n1 = 0.f, s2 = 0.f, n2 = 0.f;

  const int jbeg = jc * (N/JC);               // 1024-col chunk, 16 x 64-col steps
  const float Cexp = 1.8033688011112042f;     // 1/(TAU*ln2), TAU=0.8
  const float* prow = pos + (size_t)(i0 + r16)*N + q*4;

  f32x4 PA0, PA1, PA2, PA3, PB0, PB1, PB2, PB3;   // pos banks, static names

  // stage the 64-row j-tile of Z1+Z2 (16 KB/block, 4 insts/wave). Each inst
  // covers 8 rows: lane l -> local row r8=l>>3, source slot (l&7)^r8 (the
  // swizzle involution), LDS dest linear at base + l*16.
#define STAGEZ(BUF, JJ) { \
    const int r8 = lane >> 3; \
    const int sl = (lane & 7) ^ r8; \
    gload_lds16(Z1h + (size_t)((JJ) + w*16     + r8)*HID + sl*8, &zs1[BUF][(w*16    )*32]); \
    gload_lds16(Z1h + (size_t)((JJ) + w*16 + 8 + r8)*HID + sl*8, &zs1[BUF][(w*16 + 8)*32]); \
    gload_lds16(Z2h + (size_t)((JJ) + w*16     + r8)*HID + sl*8, &zs2[BUF][(w*16    )*32]); \
    gload_lds16(Z2h + (size_t)((JJ) + w*16 + 8 + r8)*HID + sl*8, &zs2[BUF][(w*16 + 8)*32]); \
  }

#define LOADPOS(P, JJ) { \
    P##0 = *(const f32x4*)(prow + (JJ)); \
    P##1 = *(const f32x4*)(prow + (JJ) + 16); \
    P##2 = *(const f32x4*)(prow + (JJ) + 32); \
    P##3 = *(const f32x4*)(prow + (JJ) + 48); \
  }

  // one 16x16 j-subtile: swizzled LDS fragment reads + MFMA pair + exp + acc
#define COMPC(BUF, C, CC, PV) { \
    const int R  = (CC) + (C)*16 + r16; \
    const int sw = r16 & 7; \
    bf16x8 b2lo = *(const bf16x8*)&zs2[BUF][R*32 + ((q    ) ^ sw)*4]; \
    bf16x8 b2hi = *(const bf16x8*)&zs2[BUF][R*32 + ((q + 4) ^ sw)*4]; \
    bf16x8 b1lo = *(const bf16x8*)&zs1[BUF][R*32 + ((q    ) ^ sw)*4]; \
    bf16x8 b1hi = *(const bf16x8*)&zs1[BUF][R*32 + ((q + 4) ^ sw)*4]; \
    f32x4 zero4 = {0.f,0.f,0.f,0.f}; \
    f32x4 d1 = __builtin_amdgcn_mfma_f32_16x16x32_bf16(b2lo, a1lo, zero4, 0,0,0); \
    d1       = __builtin_amdgcn_mfma_f32_16x16x32_bf16(b2hi, a1hi, d1,    0,0,0); \
    f32x4 d2 = __builtin_amdgcn_mfma_f32_16x16x32_bf16(b1lo, a2lo, zero4, 0,0,0); \
    d2       = __builtin_amdgcn_mfma_f32_16x16x32_bf16(b1hi, a2hi, d2,    0,0,0); \
    _Pragma("unroll") \
    for (int r = 0; r < 4; ++r) { \
      float e1 = exp2f(d1[r] * Cexp); \
      float e2 = exp2f(d2[r] * Cexp); \
      s1 += e1; n1 += e1 * PV[r]; \
      s2 += e2; n2 += e2 * PV[r]; \
    } }

#define STEP(BUF, P) { COMPC(BUF,0,0,P##0) COMPC(BUF,1,0,P##1) COMPC(BUF,0,32,P##2) COMPC(BUF,1,32,P##3) }

  // prologue: tile 0 in flight
  STAGEZ(0, jbeg)
  LOADPOS(PA, jbeg)
  __syncthreads();                       // vmcnt(0): tile 0 + pos(0) landed

  #pragma unroll 1
  for (int tp = 0; tp < 7; ++tp) {       // steps t = 2*tp, 2*tp+1  (0..13)
    const int t0 = tp*2;
    STAGEZ(1, jbeg + (t0+1)*64)          // issue BEFORE compute: full phase to land
    LOADPOS(PB, jbeg + (t0+1)*64)
    STEP(0, PA)
    __syncthreads();
    STAGEZ(0, jbeg + (t0+2)*64)
    LOADPOS(PA, jbeg + (t0+2)*64)
    STEP(1, PB)
    __syncthreads();
  }
  // steps 14, 15
  STAGEZ(1, jbeg + 15*64)
  LOADPOS(PB, jbeg + 15*64)
  STEP(0, PA)
  __syncthreads();
  STEP(1, PB)

#undef STAGEZ
#undef LOADPOS
#undef COMPC
#undef STEP

  // reduce j-partials across the 4 quads -> full sums per row i0+r16
  s1 += __shfl_xor(s1, 16); s1 += __shfl_xor(s1, 32);
  n1 += __shfl_xor(n1, 16); n1 += __shfl_xor(n1, 32);
  s2 += __shfl_xor(s2, 16); s2 += __shfl_xor(s2, 32);
  n2 += __shfl_xor(n2, 16); n2 += __shfl_xor(n2, 32);

  if (lane < 16) {
    int row = i0 + r16;
    atomicAdd(&rowsum1[row], s1);
    atomicAdd(&num1[row],    n1);
    atomicAdd(&rowsum2[row], s2);
    atomicAdd(&num2[row],    n2);
  }
}

// ---------------- Kernel C: final loss reduction ----------------
__global__ __launch_bounds__(1024) void loss_kernel(
    const float* __restrict__ rowsum1, const float* __restrict__ num1,
    const float* __restrict__ rowsum2, const float* __restrict__ num2,
    float* __restrict__ out)
{
  __shared__ float part[16];
  const int tid = threadIdx.x, lane = tid & 63, w = tid >> 6;
  float acc = 0.f;
  for (int i = tid; i < N; i += 1024) {
    float sc = -logf(num1[i]/(rowsum1[i]+1e-8f) + 1e-8f);
    float mp = -logf(num2[i]/(rowsum2[i]+1e-8f) + 1e-8f);
    acc += 0.5f*sc + 0.5f*mp;   // LAMBDA = 0.5
  }
  #pragma unroll
  for (int m = 1; m < 64; m <<= 1) acc += __shfl_xor(acc, m);
  if (lane == 0) part[w] = acc;
  __syncthreads();
  if (tid == 0) {
    float t = 0.f;
    #pragma unroll
    for (int k = 0; k < 16; ++k) t += part[k];
    out[0] = t * (1.0f/N);
  }
}

extern "C" void kernel_launch(void* const* d_in, const int* in_sizes, int n_in,
                              void* d_out, int out_size, void* d_ws, size_t ws_size,
                              hipStream_t stream) {
  const float* x1  = (const float*)d_in[0];
  const float* x2  = (const float*)d_in[1];
  const float* W1  = (const float*)d_in[2];
  const float* b1  = (const float*)d_in[3];
  const float* W2  = (const float*)d_in[4];
  const float* b2  = (const float*)d_in[5];
  const float* pos = (const float*)d_in[6];

  char* ws = (char*)d_ws;
  __bf16* Z1h = (__bf16*)ws;
  __bf16* Z2h = (__bf16*)(ws + (size_t)N*HID*sizeof(__bf16));
  size_t zbytes = (size_t)2*N*HID*sizeof(__bf16);   // 2 MB
  float* rowsum1 = (float*)(ws + zbytes);
  float* num1    = rowsum1 + N;
  float* rowsum2 = num1 + N;
  float* num2    = rowsum2 + N;

  proj_kernel<<<1024, 256, 0, stream>>>(x1, x2, W1, b1, W2, b2, Z1h, Z2h, rowsum1);
  sim_kernel<<<128*JC, 256, 0, stream>>>(Z1h, Z2h, pos, rowsum1, num1, rowsum2, num2);
  loss_kernel<<<1, 1024, 0, stream>>>(rowsum1, num1, rowsum2, num2, (float*)d_out);
}